// Round 2
// baseline (503.992 us; speedup 1.0000x reference)
//
#include <hip/hip_runtime.h>
#include <hip/hip_fp16.h>

#define BATCH 8
#define MAX_SEQ 2048
#define HEAD_NUM 8

typedef float vfloat4 __attribute__((ext_vector_type(4)));
typedef int   vint4   __attribute__((ext_vector_type(4)));

// One block = 1024 consecutive elements of one batch's s x s crop (row-major).
// Each thread: 1 float4 load, fp16-round + >0.5 compare, 8 int4 stores
// (one per head, stride s*s in the packed int32 output).
__global__ __launch_bounds__(256) void genmask_kernel(
    const float* __restrict__ mask,   // (BATCH, 1, MAX_SEQ, MAX_SEQ) f32
    const int*   __restrict__ sl,     // (BATCH,) int32 seq lengths
    int*         __restrict__ out)    // packed output, int32 0/1 (bool)
{
    const unsigned int blk = blockIdx.x;

    // Find which batch this block belongs to (scalar, wave-uniform).
    unsigned long long out_base = 0;      // element offset of batch b's region in out
    unsigned int blocks_before = 0;       // #blocks consumed by earlier batches
    unsigned int s = 0;
    int b = 0;
    for (; b < BATCH; ++b) {
        s = (unsigned int)sl[b];
        const unsigned int nb = (s * s) >> 10;          // 1024 elems per block
        if (blk < blocks_before + nb) break;
        blocks_before += nb;
        out_base += (unsigned long long)HEAD_NUM * s * s;
    }

    // Linear element index within this batch's s x s crop.
    const unsigned int local = (blk - blocks_before) * 1024u + threadIdx.x * 4u;
    const unsigned int i = local / s;          // row in crop
    const unsigned int j = local - i * s;      // col in crop (multiple of 4: s%4==0)

    const vfloat4 v = *(const vfloat4*)(mask
        + (size_t)b * MAX_SEQ * MAX_SEQ
        + (size_t)i * MAX_SEQ + j);

    // Replicate astype(float16) then > 0.5 exactly: RTNE f32->f16 first.
    vint4 r;
    r.x = (__half2float(__float2half(v.x)) > 0.5f) ? 1 : 0;
    r.y = (__half2float(__float2half(v.y)) > 0.5f) ? 1 : 0;
    r.z = (__half2float(__float2half(v.z)) > 0.5f) ? 1 : 0;
    r.w = (__half2float(__float2half(v.w)) > 0.5f) ? 1 : 0;

    const unsigned long long ss4 = ((unsigned long long)s * s) >> 2;  // head stride in int4s
    vint4* o = (vint4*)(out + out_base + local);
    #pragma unroll
    for (int h = 0; h < HEAD_NUM; ++h) {
        __builtin_nontemporal_store(r, o);
        o += ss4;
    }
}

extern "C" void kernel_launch(void* const* d_in, const int* in_sizes, int n_in,
                              void* d_out, int out_size, void* d_ws, size_t ws_size,
                              hipStream_t stream) {
    const float* mask = (const float*)d_in[0];
    const int*   sl   = (const int*)d_in[1];
    int*         out  = (int*)d_out;

    // Total input-crop elements = out_size / HEAD_NUM; 1024 elems per block.
    const unsigned int n_blocks =
        (unsigned int)((long long)out_size / (HEAD_NUM * 1024));

    genmask_kernel<<<n_blocks, 256, 0, stream>>>(mask, sl, out);
}

// Round 3
// 479.658 us; speedup vs baseline: 1.0507x; 1.0507x over previous
//
#include <hip/hip_runtime.h>
#include <hip/hip_fp16.h>

#define BATCH 8
#define MAX_SEQ 2048
#define HEAD_NUM 8

typedef float vfloat4 __attribute__((ext_vector_type(4)));
typedef int   vint4   __attribute__((ext_vector_type(4)));

// Output-linear mapping: one block = 1024 consecutive OUTPUT elements, so the
// 428 MB output is written as one sequential stream (memset-like, 6.3 TB/s
// pattern). Reads re-fetch each batch's s x s crop once per head; all crops
// total 53.5 MB << 256 MB L3, so re-reads are Infinity-Cache hits.
__global__ __launch_bounds__(256) void genmask_kernel(
    const float* __restrict__ mask,   // (BATCH, 1, MAX_SEQ, MAX_SEQ) f32
    const int*   __restrict__ sl,     // (BATCH,) int32 seq lengths
    int*         __restrict__ out)    // packed output, int32 0/1 (bool)
{
    const unsigned int blk = blockIdx.x;

    // Which batch does this block's output chunk belong to? (wave-uniform)
    unsigned long long out_base = 0;      // element offset of batch b's region
    unsigned int blocks_before = 0;
    unsigned int s = 0;
    int b = 0;
    for (; b < BATCH; ++b) {
        s = (unsigned int)sl[b];
        // 8 heads * s^2 elems per batch, 1024 elems per block (s^2 % 1024 == 0)
        const unsigned int nb = (HEAD_NUM * (s * s)) >> 10;
        if (blk < blocks_before + nb) break;
        blocks_before += nb;
        out_base += (unsigned long long)HEAD_NUM * s * s;
    }

    // Linear index within this batch's output region [0, 8*s*s).
    const unsigned int local = (blk - blocks_before) * 1024u + threadIdx.x * 4u;
    const unsigned int ss  = s * s;
    const unsigned int h   = local / ss;       // head (unused for addressing input)
    const unsigned int rem = local - h * ss;   // index within s x s crop
    const unsigned int i   = rem / s;          // row
    const unsigned int j   = rem - i * s;      // col (multiple of 4)

    const vfloat4 v = *(const vfloat4*)(mask
        + (size_t)b * MAX_SEQ * MAX_SEQ
        + (size_t)i * MAX_SEQ + j);

    // Replicate astype(float16) then > 0.5 exactly: RTNE f32->f16 first.
    vint4 r;
    r.x = (__half2float(__float2half(v.x)) > 0.5f) ? 1 : 0;
    r.y = (__half2float(__float2half(v.y)) > 0.5f) ? 1 : 0;
    r.z = (__half2float(__float2half(v.z)) > 0.5f) ? 1 : 0;
    r.w = (__half2float(__float2half(v.w)) > 0.5f) ? 1 : 0;

    __builtin_nontemporal_store(r, (vint4*)(out + out_base + local));
}

extern "C" void kernel_launch(void* const* d_in, const int* in_sizes, int n_in,
                              void* d_out, int out_size, void* d_ws, size_t ws_size,
                              hipStream_t stream) {
    const float* mask = (const float*)d_in[0];
    const int*   sl   = (const int*)d_in[1];
    int*         out  = (int*)d_out;

    // 1024 output elements per block.
    const unsigned int n_blocks = (unsigned int)(out_size / 1024);

    genmask_kernel<<<n_blocks, 256, 0, stream>>>(mask, sl, out);
}